// Round 1
// baseline (936.059 us; speedup 1.0000x reference)
//
#include <hip/hip_runtime.h>
#include <stdint.h>

typedef unsigned short u16;
typedef __attribute__((ext_vector_type(4))) float f32x4;
typedef __attribute__((ext_vector_type(8))) short s16x8;
typedef __attribute__((ext_vector_type(4))) unsigned short u16x4;

#define HW   3600
#define HWP  3648
#define DIM  256
#define CIN  1536
#define QLD  512   // q_ext/k_ext row stride: [hi(256) | lo(256)]
#define BM   128
#define BN   128
#define BK   64
#define LDK  72    // padded LDS stride (bank-conflict avoidance)

__device__ __forceinline__ u16 f2bf(float f) {
  uint32_t u = __float_as_uint(f);
  uint32_t r = (u + 0x7fffu + ((u >> 16) & 1u)) >> 16;
  return (u16)r;
}
__device__ __forceinline__ float bf2f(u16 h) { return __uint_as_float((uint32_t)h << 16); }
__device__ __forceinline__ u16 f2bf_lo(float f) {
  float hi = bf2f(f2bf(f));
  return f2bf(f - hi);
}

// MFMA inner loop over one staged 128x64 (K) tile. As: [row][k], Bs: [col][k].
__device__ __forceinline__ void mfma_tile(const u16 (*As)[LDK], const u16 (*Bs)[LDK],
                                          int lane, int wr, int wc, f32x4 acc[4][4]) {
#pragma unroll
  for (int ks = 0; ks < 2; ++ks) {
    const int ko = ks * 32 + ((lane >> 4) << 3);
    s16x8 af[4], bv[4];
#pragma unroll
    for (int m = 0; m < 4; ++m) af[m] = *(const s16x8*)&As[wr + m * 16 + (lane & 15)][ko];
#pragma unroll
    for (int n = 0; n < 4; ++n) bv[n] = *(const s16x8*)&Bs[wc + n * 16 + (lane & 15)][ko];
#pragma unroll
    for (int m = 0; m < 4; ++m)
#pragma unroll
      for (int n = 0; n < 4; ++n)
        acc[m][n] = __builtin_amdgcn_mfma_f32_16x16x32_bf16(af[m], bv[n], acc[m][n], 0, 0, 0);
  }
}

// ---------------- prep: bg suppression from mask (exact 8x subsample) ----------------
__global__ __launch_bounds__(256) void k_prep(const float* __restrict__ mask,
                                              float* __restrict__ sup) {
  int i = blockIdx.x * 256 + threadIdx.x;
  if (i < 4 * HW) {
    int b = i / HW, p = i % HW, py = p / 60, px = p % 60;
    float fg = mask[(size_t)b * 473 * 473 + (size_t)(py * 8) * 473 + px * 8];
    sup[i] = (1.0f - fg) * -999.0f;
  }
}

// ---------------- conv_v: v = W_lpf @ feat (plain bf16) ----------------
// vs: [b][256][HWP] (for PV B operand); vq: [b][HW][256] (for final A operand)
__global__ __launch_bounds__(256) void k_conv_v(
    const float* __restrict__ Wlpf, const float* __restrict__ featS,
    const float* __restrict__ featQ, u16* __restrict__ vs, u16* __restrict__ vq) {
  const int tid = threadIdx.x, lane = tid & 63, wid = tid >> 6;
  const int wr = (wid >> 1) << 6, wc = (wid & 1) << 6;
  const int rowBase = blockIdx.x * BM;           // output channel o
  const int colBase = blockIdx.y * BN;           // pixel
  const int b = blockIdx.z & 3, isQ = blockIdx.z >> 2;
  const float* feat = (isQ ? featQ : featS) + (size_t)b * CIN * HW;

  __shared__ u16 As[BM][LDK];
  __shared__ u16 Bs[BN][LDK];
  f32x4 acc[4][4] = {};

  const int a_kv = (tid & 15) << 2, a_r0 = tid >> 4;
  const int b_n = tid & 127, b_kh = (tid >> 7) << 5;
  const int gnc = colBase + b_n;
  const int gn = gnc < HW ? gnc : HW - 1;

  for (int kt = 0; kt < CIN / BK; ++kt) {
    const int k0 = kt * BK;
#pragma unroll
    for (int i = 0; i < 8; ++i) {
      const float* s = Wlpf + (size_t)(rowBase + a_r0 + i * 16) * CIN + k0 + a_kv;
      f32x4 v = *(const f32x4*)s;
      u16x4 h = {f2bf(v[0]), f2bf(v[1]), f2bf(v[2]), f2bf(v[3])};
      *(u16x4*)&As[a_r0 + i * 16][a_kv] = h;
    }
#pragma unroll
    for (int g = 0; g < 8; ++g) {
      const float* s = feat + (size_t)(k0 + b_kh + g * 4) * HW + gn;
      u16x4 h = {f2bf(s[0]), f2bf(s[HW]), f2bf(s[2 * HW]), f2bf(s[3 * HW])};
      *(u16x4*)&Bs[b_n][b_kh + g * 4] = h;
    }
    __syncthreads();
    mfma_tile(As, Bs, lane, wr, wc, acc);
    __syncthreads();
  }
  if (!isQ) {
    u16* dst = vs + (size_t)b * DIM * HWP;
#pragma unroll
    for (int m = 0; m < 4; ++m) {
      const int o = rowBase + wr + m * 16 + ((lane >> 4) << 2);
#pragma unroll
      for (int n = 0; n < 4; ++n) {
        const int pix = colBase + wc + n * 16 + (lane & 15);
        if (pix < HW) {
#pragma unroll
          for (int r = 0; r < 4; ++r) dst[(size_t)(o + r) * HWP + pix] = f2bf(acc[m][n][r]);
        }
      }
    }
  } else {
    u16* dst = vq + (size_t)b * HW * DIM;
#pragma unroll
    for (int m = 0; m < 4; ++m) {
      const int o = rowBase + wr + m * 16 + ((lane >> 4) << 2);
#pragma unroll
      for (int n = 0; n < 4; ++n) {
        const int pix = colBase + wc + n * 16 + (lane & 15);
        if (pix < HW) {
          u16x4 h = {f2bf(acc[m][n][0]), f2bf(acc[m][n][1]),
                     f2bf(acc[m][n][2]), f2bf(acc[m][n][3])};
          *(u16x4*)&dst[(size_t)pix * DIM + o] = h;
        }
      }
    }
  }
}

// ---------------- conv_qk: q/k = W @ feat with hi/lo split (3-term, K'=3*1536) ----------
// output layout: [b][pix][hi(256)|lo(256)]
__global__ __launch_bounds__(256) void k_conv_qk(
    const float* __restrict__ Wsupp, const float* __restrict__ Wquery,
    const float* __restrict__ featS, const float* __restrict__ featQ,
    u16* __restrict__ k_ext, u16* __restrict__ q_ext) {
  const int tid = threadIdx.x, lane = tid & 63, wid = tid >> 6;
  const int wr = (wid >> 1) << 6, wc = (wid & 1) << 6;
  const int rowBase = blockIdx.x * BM;
  const int colBase = blockIdx.y * BN;
  const int b = blockIdx.z & 3, isQ = blockIdx.z >> 2;
  const float* Wm = isQ ? Wquery : Wsupp;
  const float* feat = (isQ ? featQ : featS) + (size_t)b * CIN * HW;
  u16* dst = (isQ ? q_ext : k_ext) + (size_t)b * HW * QLD;

  __shared__ u16 As[BM][LDK];
  __shared__ u16 Bs[BN][LDK];
  f32x4 acc[4][4] = {};

  const int a_kv = (tid & 15) << 2, a_r0 = tid >> 4;
  const int b_n = tid & 127, b_kh = (tid >> 7) << 5;
  const int gnc = colBase + b_n;
  const int gn = gnc < HW ? gnc : HW - 1;

  for (int kt = 0; kt < 72; ++kt) {              // 3 phases x 24 tiles
    const int p = kt / 24;
    const int k0 = (kt % 24) * BK;
    const bool aLo = (p == 2), bLo = (p == 1);
#pragma unroll
    for (int i = 0; i < 8; ++i) {
      const float* s = Wm + (size_t)(rowBase + a_r0 + i * 16) * CIN + k0 + a_kv;
      f32x4 v = *(const f32x4*)s;
      u16x4 h;
      if (aLo) h = (u16x4){f2bf_lo(v[0]), f2bf_lo(v[1]), f2bf_lo(v[2]), f2bf_lo(v[3])};
      else     h = (u16x4){f2bf(v[0]), f2bf(v[1]), f2bf(v[2]), f2bf(v[3])};
      *(u16x4*)&As[a_r0 + i * 16][a_kv] = h;
    }
#pragma unroll
    for (int g = 0; g < 8; ++g) {
      const float* s = feat + (size_t)(k0 + b_kh + g * 4) * HW + gn;
      float v0 = s[0], v1 = s[HW], v2 = s[2 * HW], v3 = s[3 * HW];
      u16x4 h;
      if (bLo) h = (u16x4){f2bf_lo(v0), f2bf_lo(v1), f2bf_lo(v2), f2bf_lo(v3)};
      else     h = (u16x4){f2bf(v0), f2bf(v1), f2bf(v2), f2bf(v3)};
      *(u16x4*)&Bs[b_n][b_kh + g * 4] = h;
    }
    __syncthreads();
    mfma_tile(As, Bs, lane, wr, wc, acc);
    __syncthreads();
  }
#pragma unroll
  for (int m = 0; m < 4; ++m) {
    const int o = rowBase + wr + m * 16 + ((lane >> 4) << 2);
#pragma unroll
    for (int n = 0; n < 4; ++n) {
      const int pix = colBase + wc + n * 16 + (lane & 15);
      if (pix < HW) {
        u16x4 hi, lo;
#pragma unroll
        for (int r = 0; r < 4; ++r) {
          float a = acc[m][n][r];
          hi[r] = f2bf(a);
          lo[r] = f2bf(a - bf2f(hi[r]));
        }
        *(u16x4*)&dst[(size_t)pix * QLD + o] = hi;
        *(u16x4*)&dst[(size_t)pix * QLD + 256 + o] = lo;
      }
    }
  }
}

// ---------------- qk: logits = q.k^T (3-term split, K'=768) + sup, fp32 out -----------
__global__ __launch_bounds__(256) void k_qk(
    const u16* __restrict__ q_ext, const u16* __restrict__ k_ext,
    const float* __restrict__ sup, float* __restrict__ attn) {
  const int tid = threadIdx.x, lane = tid & 63, wid = tid >> 6;
  const int wr = (wid >> 1) << 6, wc = (wid & 1) << 6;
  const int rowBase = blockIdx.x * BM;           // q pixel
  const int colBase = blockIdx.y * BN;           // k pixel
  const int b = blockIdx.z;
  const u16* Aq = q_ext + (size_t)b * HW * QLD;
  const u16* Bk = k_ext + (size_t)b * HW * QLD;

  __shared__ u16 As[BM][LDK];
  __shared__ u16 Bs[BN][LDK];
  f32x4 acc[4][4] = {};

  const int kv8 = (tid & 7) << 3, r0 = tid >> 3;

  for (int kt = 0; kt < 12; ++kt) {              // phases: (qh,kh) (qh,kl) (ql,kh)
    const int p = kt >> 2;
    const int kk = (kt & 3) * BK;
    const int aOff = (p < 2 ? 0 : 256) + kk;
    const int bOff = (p == 1 ? 256 : 0) + kk;
#pragma unroll
    for (int i = 0; i < 4; ++i) {
      int r = r0 + i * 32;
      int ga = rowBase + r; ga = ga < HW ? ga : HW - 1;
      *(s16x8*)&As[r][kv8] = *(const s16x8*)(Aq + (size_t)ga * QLD + aOff + kv8);
      int gb = colBase + r; gb = gb < HW ? gb : HW - 1;
      *(s16x8*)&Bs[r][kv8] = *(const s16x8*)(Bk + (size_t)gb * QLD + bOff + kv8);
    }
    __syncthreads();
    mfma_tile(As, Bs, lane, wr, wc, acc);
    __syncthreads();
  }
  float* out = attn + (size_t)b * HW * HW;
#pragma unroll
  for (int n = 0; n < 4; ++n) {
    const int kp = colBase + wc + n * 16 + (lane & 15);
    if (kp >= HW) continue;
    const float sp = sup[b * HW + kp];
#pragma unroll
    for (int m = 0; m < 4; ++m) {
      const int qp = rowBase + wr + m * 16 + ((lane >> 4) << 2);
      if (qp < HW) {
#pragma unroll
        for (int r = 0; r < 4; ++r) out[(size_t)(qp + r) * HW + kp] = acc[m][n][r] + sp;
      }
    }
  }
}

// ---------------- softmax: one block per row, in-place on attn ----------------
__global__ __launch_bounds__(256) void k_softmax(float* __restrict__ attn) {
  const size_t row = blockIdx.x;
  float* rp = attn + row * HW;
  const int t = threadIdx.x;
  f32x4 v[4];
  float m = -3.4e38f;
#pragma unroll
  for (int i = 0; i < 4; ++i) {
    const int idx = t + i * 256;
    if (idx < 900) {
      v[i] = *(const f32x4*)(rp + idx * 4);
      m = fmaxf(m, fmaxf(fmaxf(v[i][0], v[i][1]), fmaxf(v[i][2], v[i][3])));
    }
  }
#pragma unroll
  for (int off = 32; off > 0; off >>= 1) m = fmaxf(m, __shfl_xor(m, off));
  __shared__ float redM[4], redS[4];
  if ((t & 63) == 0) redM[t >> 6] = m;
  __syncthreads();
  m = fmaxf(fmaxf(redM[0], redM[1]), fmaxf(redM[2], redM[3]));
  float s = 0.f;
#pragma unroll
  for (int i = 0; i < 4; ++i) {
    const int idx = t + i * 256;
    if (idx < 900) {
#pragma unroll
      for (int c = 0; c < 4; ++c) { v[i][c] = expf(v[i][c] - m); s += v[i][c]; }
    }
  }
#pragma unroll
  for (int off = 32; off > 0; off >>= 1) s += __shfl_xor(s, off);
  if ((t & 63) == 0) redS[t >> 6] = s;
  __syncthreads();
  const float inv = 1.f / (redS[0] + redS[1] + redS[2] + redS[3]);
#pragma unroll
  for (int i = 0; i < 4; ++i) {
    const int idx = t + i * 256;
    if (idx < 900) {
      f32x4 w = v[i] * inv;
      *(f32x4*)(rp + idx * 4) = w;
    }
  }
}

// ---------------- pv: ov = attn @ vs (bf16), attn read fp32 with K-tail guard ---------
__global__ __launch_bounds__(256) void k_pv(
    const float* __restrict__ attn, const u16* __restrict__ vs, u16* __restrict__ ov) {
  const int tid = threadIdx.x, lane = tid & 63, wid = tid >> 6;
  const int wr = (wid >> 1) << 6, wc = (wid & 1) << 6;
  const int rowBase = blockIdx.x * BM;           // q pixel
  const int colBase = blockIdx.y * BN;           // d
  const int b = blockIdx.z;
  const float* Ab = attn + (size_t)b * HW * HW;
  const u16* Bv = vs + (size_t)b * DIM * HWP;

  __shared__ u16 As[BM][LDK];
  __shared__ u16 Bs[BN][LDK];
  f32x4 acc[4][4] = {};

  const int a_kv = (tid & 15) << 2, a_r0 = tid >> 4;
  const int kv8 = (tid & 7) << 3, r0 = tid >> 3;

  for (int kt = 0; kt < 57; ++kt) {              // ceil(3600/64); tail zero-padded
    const int k0 = kt * BK;
    const int kc = k0 + a_kv;
#pragma unroll
    for (int i = 0; i < 8; ++i) {
      int r = a_r0 + i * 16;
      int ga = rowBase + r; ga = ga < HW ? ga : HW - 1;
      u16x4 h = {0, 0, 0, 0};
      if (kc < HW) {
        f32x4 vv = *(const f32x4*)(Ab + (size_t)ga * HW + kc);
        h = (u16x4){f2bf(vv[0]), f2bf(vv[1]), f2bf(vv[2]), f2bf(vv[3])};
      }
      *(u16x4*)&As[r][a_kv] = h;
    }
#pragma unroll
    for (int i = 0; i < 4; ++i) {
      int r = r0 + i * 32;
      *(s16x8*)&Bs[r][kv8] = *(const s16x8*)(Bv + (size_t)(colBase + r) * HWP + k0 + kv8);
    }
    __syncthreads();
    mfma_tile(As, Bs, lane, wr, wc, acc);
    __syncthreads();
  }
  u16* dst = ov + (size_t)b * HW * DIM;
#pragma unroll
  for (int m = 0; m < 4; ++m) {
    const int pix0 = rowBase + wr + m * 16 + ((lane >> 4) << 2);
    if (pix0 >= HW) continue;
#pragma unroll
    for (int n = 0; n < 4; ++n) {
      const int d = colBase + wc + n * 16 + (lane & 15);
#pragma unroll
      for (int r = 0; r < 4; ++r) dst[(size_t)(pix0 + r) * DIM + d] = f2bf(acc[m][n][r]);
    }
  }
}

// ---------------- final: relu(Wf @ [ov|vq] + b) -> [b][o][pix] fp32 -------------------
__global__ __launch_bounds__(256) void k_final(
    const u16* __restrict__ ov, const u16* __restrict__ vq,
    const float* __restrict__ Wfin, const float* __restrict__ bfin,
    float* __restrict__ outF) {
  const int tid = threadIdx.x, lane = tid & 63, wid = tid >> 6;
  const int wr = (wid >> 1) << 6, wc = (wid & 1) << 6;
  const int rowBase = blockIdx.x * BM;           // pixel
  const int colBase = blockIdx.y * BN;           // o
  const int b = blockIdx.z;
  const u16* Aov = ov + (size_t)b * HW * DIM;
  const u16* Avq = vq + (size_t)b * HW * DIM;

  __shared__ u16 As[BM][LDK];
  __shared__ u16 Bs[BN][LDK];
  f32x4 acc[4][4] = {};

  const int kv8 = (tid & 7) << 3, r0 = tid >> 3;
  const int b_kv = (tid & 15) << 2, b_r0 = tid >> 4;

  for (int kt = 0; kt < 8; ++kt) {
    const int k0 = kt * BK;
    const u16* Asrc = (k0 < 256) ? Aov : Avq;
    const int ak = k0 & 255;
#pragma unroll
    for (int i = 0; i < 4; ++i) {
      int r = r0 + i * 32;
      int ga = rowBase + r; ga = ga < HW ? ga : HW - 1;
      *(s16x8*)&As[r][kv8] = *(const s16x8*)(Asrc + (size_t)ga * DIM + ak + kv8);
    }
#pragma unroll
    for (int i = 0; i < 8; ++i) {
      const float* s = Wfin + (size_t)(colBase + b_r0 + i * 16) * 512 + k0 + b_kv;
      f32x4 v = *(const f32x4*)s;
      u16x4 h = {f2bf(v[0]), f2bf(v[1]), f2bf(v[2]), f2bf(v[3])};
      *(u16x4*)&Bs[b_r0 + i * 16][b_kv] = h;
    }
    __syncthreads();
    mfma_tile(As, Bs, lane, wr, wc, acc);
    __syncthreads();
  }
  float* dst = outF + (size_t)b * DIM * HW;
#pragma unroll
  for (int n = 0; n < 4; ++n) {
    const int o = colBase + wc + n * 16 + (lane & 15);
    const float bb = bfin[o];
#pragma unroll
    for (int m = 0; m < 4; ++m) {
      const int pix0 = rowBase + wr + m * 16 + ((lane >> 4) << 2);
      if (pix0 < HW) {
        f32x4 v;
#pragma unroll
        for (int r = 0; r < 4; ++r) v[r] = fmaxf(acc[m][n][r] + bb, 0.f);
        *(f32x4*)(dst + (size_t)o * HW + pix0) = v;
      }
    }
  }
}

extern "C" void kernel_launch(void* const* d_in, const int* in_sizes, int n_in,
                              void* d_out, int out_size, void* d_ws, size_t ws_size,
                              hipStream_t stream) {
  (void)in_sizes; (void)n_in; (void)out_size; (void)ws_size;
  const float* featS  = (const float*)d_in[0];
  const float* featQ  = (const float*)d_in[1];
  const float* mask   = (const float*)d_in[2];
  const float* Wlpf   = (const float*)d_in[3];
  const float* Wsupp  = (const float*)d_in[4];
  const float* Wquery = (const float*)d_in[5];
  const float* Wfin   = (const float*)d_in[6];
  const float* bfin   = (const float*)d_in[7];

  float* outF = (float*)d_out;
  float* attn = outF + (size_t)4 * DIM * HW;     // output 1 region doubles as logits scratch

  char* w = (char*)d_ws;
  u16* q_ext = (u16*)w;  w += (size_t)4 * HW * QLD * 2;
  u16* k_ext = (u16*)w;  w += (size_t)4 * HW * QLD * 2;
  u16* vs    = (u16*)w;  w += (size_t)4 * DIM * HWP * 2;
  u16* vq    = (u16*)w;  w += (size_t)4 * HW * DIM * 2;
  u16* ov    = (u16*)w;  w += (size_t)4 * HW * DIM * 2;
  float* sup = (float*)w;

  k_prep<<<dim3((4 * HW + 255) / 256), 256, 0, stream>>>(mask, sup);
  k_conv_v<<<dim3(2, 29, 8), 256, 0, stream>>>(Wlpf, featS, featQ, vs, vq);
  k_conv_qk<<<dim3(2, 29, 8), 256, 0, stream>>>(Wsupp, Wquery, featS, featQ, k_ext, q_ext);
  k_qk<<<dim3(29, 29, 4), 256, 0, stream>>>(q_ext, k_ext, sup, attn);
  k_softmax<<<dim3(4 * HW), 256, 0, stream>>>(attn);
  k_pv<<<dim3(29, 2, 4), 256, 0, stream>>>(attn, vs, ov);
  k_final<<<dim3(29, 2, 4), 256, 0, stream>>>(ov, vq, Wfin, bfin, outF);
}

// Round 2
// 399.434 us; speedup vs baseline: 2.3435x; 2.3435x over previous
//
#include <hip/hip_runtime.h>
#include <stdint.h>

typedef unsigned short u16;
typedef _Float16 h16;
typedef __attribute__((ext_vector_type(4))) float f32x4;
typedef __attribute__((ext_vector_type(8))) short s16x8;
typedef __attribute__((ext_vector_type(8))) _Float16 h16x8;
typedef __attribute__((ext_vector_type(4))) _Float16 h16x4;

#define HW   3600
#define HWP  3648
#define DIM  256
#define CIN  1536
#define LDK  72    // padded LDS stride in elements (144B rows, 16B-aligned, conflict-free)

// ---- MFMA inner loop over one staged [.. ][64] K-tile. As: [row][k], Bs: [col][k]. ----
template<int MR, int NR>
__device__ __forceinline__ void mfma_tile(const h16 (*As)[LDK], const h16 (*Bs)[LDK],
                                          int lane, int wr, int wc, f32x4 acc[MR][NR]) {
#pragma unroll
  for (int ks = 0; ks < 2; ++ks) {
    const int ko = ks * 32 + ((lane >> 4) << 3);
    h16x8 af[MR], bv[NR];
#pragma unroll
    for (int m = 0; m < MR; ++m) af[m] = *(const h16x8*)&As[wr + m * 16 + (lane & 15)][ko];
#pragma unroll
    for (int n = 0; n < NR; ++n) bv[n] = *(const h16x8*)&Bs[wc + n * 16 + (lane & 15)][ko];
#pragma unroll
    for (int m = 0; m < MR; ++m)
#pragma unroll
      for (int n = 0; n < NR; ++n)
        acc[m][n] = __builtin_amdgcn_mfma_f32_16x16x32_f16(af[m], bv[n], acc[m][n], 0, 0, 0);
  }
}

// ---------------- prep: sup from mask + fp16 weight conversion + vs pad zero -----------
#define NW    (256 * 1536)
#define NWF   (256 * 512)
#define NPAD  (4 * 256 * 48)
#define NPREP (14400 + 3 * NW + NWF + NPAD)

__global__ __launch_bounds__(256) void k_prep(
    const float* __restrict__ mask, const float* __restrict__ Wlpf,
    const float* __restrict__ Wsupp, const float* __restrict__ Wquery,
    const float* __restrict__ Wfin,
    float* __restrict__ sup, h16* __restrict__ Wl16, h16* __restrict__ Ws16,
    h16* __restrict__ Wq16, h16* __restrict__ Wf16, h16* __restrict__ vs) {
  int i = blockIdx.x * 256 + threadIdx.x;
  if (i < 14400) {
    int b = i / HW, p = i % HW, py = p / 60, px = p % 60;
    float fg = mask[(size_t)b * 473 * 473 + (size_t)(py * 8) * 473 + px * 8];
    sup[i] = (1.0f - fg) * -999.0f;
  } else if (i < 14400 + NW) {
    int j = i - 14400; Wl16[j] = (h16)Wlpf[j];
  } else if (i < 14400 + 2 * NW) {
    int j = i - 14400 - NW; Ws16[j] = (h16)Wsupp[j];
  } else if (i < 14400 + 3 * NW) {
    int j = i - 14400 - 2 * NW; Wq16[j] = (h16)Wquery[j];
  } else if (i < 14400 + 3 * NW + NWF) {
    int j = i - 14400 - 3 * NW; Wf16[j] = (h16)Wfin[j];
  } else if (i < NPREP) {
    int j = i - 14400 - 3 * NW - NWF;
    int b = j / (256 * 48), rem = j % (256 * 48), d = rem / 48, kk = rem % 48;
    vs[((size_t)b * DIM + d) * HWP + 3600 + kk] = (h16)0.0f;
  }
}

// ---------------- fused conv: [lpf(256) ; supp/query(256)] @ feat, fp16 ----------------
__global__ __launch_bounds__(256) void k_conv(
    const h16* __restrict__ Wl16, const h16* __restrict__ Ws16, const h16* __restrict__ Wq16,
    const float* __restrict__ featS, const float* __restrict__ featQ,
    h16* __restrict__ vs, h16* __restrict__ vq,
    h16* __restrict__ kbuf, h16* __restrict__ qbuf) {
  const int tid = threadIdx.x, lane = tid & 63, wid = tid >> 6;
  const int wr = (wid >> 1) << 6, wc = (wid & 1) << 6;
  const int rowBase = blockIdx.x * 128;          // output row in [0,512): <256 lpf, >=256 side
  const int colBase = blockIdx.y * 128;          // pixel
  const int b = blockIdx.z & 3, isQ = blockIdx.z >> 2;
  const bool isV = rowBase < 256;
  const h16* Wbase = isV ? (Wl16 + (size_t)rowBase * CIN)
                         : ((isQ ? Wq16 : Ws16) + (size_t)(rowBase - 256) * CIN);
  const float* feat = (isQ ? featQ : featS) + (size_t)b * CIN * HW;

  __shared__ h16 As[128][LDK];
  __shared__ h16 Bs[128][LDK];
  f32x4 acc[4][4] = {};

  const int a_r = tid >> 3, a_kv = (tid & 7) << 3;
  const int b_n = tid & 127, b_kh = (tid >> 7) << 5;
  const int gnc = colBase + b_n;
  const int gn = gnc < HW ? gnc : HW - 1;

  for (int kt = 0; kt < 24; ++kt) {
    const int k0 = kt * 64;
#pragma unroll
    for (int i = 0; i < 4; ++i) {
      const int r = a_r + i * 32;
      *(s16x8*)&As[r][a_kv] = *(const s16x8*)&Wbase[(size_t)r * CIN + k0 + a_kv];
    }
#pragma unroll
    for (int g = 0; g < 8; ++g) {
      const float* s = feat + (size_t)(k0 + b_kh + g * 4) * HW + gn;
      h16x4 h = {(h16)s[0], (h16)s[HW], (h16)s[2 * HW], (h16)s[3 * HW]};
      *(h16x4*)&Bs[b_n][b_kh + g * 4] = h;
    }
    __syncthreads();
    mfma_tile<4, 4>(As, Bs, lane, wr, wc, acc);
    __syncthreads();
  }

  if (isV && !isQ) {            // vs: [b][d][HWP] (transposed, PV B-operand)
    h16* dst = vs + (size_t)b * DIM * HWP;
#pragma unroll
    for (int m = 0; m < 4; ++m) {
      const int d0 = rowBase + wr + m * 16 + ((lane >> 4) << 2);
#pragma unroll
      for (int n = 0; n < 4; ++n) {
        const int pix = colBase + wc + n * 16 + (lane & 15);
        if (pix < HW) {
#pragma unroll
          for (int r = 0; r < 4; ++r) dst[(size_t)(d0 + r) * HWP + pix] = (h16)acc[m][n][r];
        }
      }
    }
  } else {                      // vq / kbuf / qbuf: [b][pix][256]
    h16* dst = (isV ? vq : (isQ ? qbuf : kbuf)) + (size_t)b * HW * DIM;
    const int dOff = isV ? 0 : -256;
#pragma unroll
    for (int m = 0; m < 4; ++m) {
      const int d0 = rowBase + wr + m * 16 + ((lane >> 4) << 2) + dOff;
#pragma unroll
      for (int n = 0; n < 4; ++n) {
        const int pix = colBase + wc + n * 16 + (lane & 15);
        if (pix < HW) {
          h16x4 h = {(h16)acc[m][n][0], (h16)acc[m][n][1],
                     (h16)acc[m][n][2], (h16)acc[m][n][3]};
          *(h16x4*)&dst[(size_t)pix * DIM + d0] = h;
        }
      }
    }
  }
}

// ---------------- qk: logits = q.k^T + sup, fp32 out ----------------
__global__ __launch_bounds__(256) void k_qk(
    const h16* __restrict__ qbuf, const h16* __restrict__ kbuf,
    const float* __restrict__ sup, float* __restrict__ attn) {
  const int tid = threadIdx.x, lane = tid & 63, wid = tid >> 6;
  const int wr = (wid >> 1) << 6, wc = (wid & 1) << 6;
  const int rowBase = blockIdx.x * 128;          // q pixel
  const int colBase = blockIdx.y * 128;          // k pixel
  const int b = blockIdx.z;
  const h16* Aq = qbuf + (size_t)b * HW * DIM;
  const h16* Bk = kbuf + (size_t)b * HW * DIM;

  __shared__ h16 As[128][LDK];
  __shared__ h16 Bs[128][LDK];
  f32x4 acc[4][4] = {};

  const int r0 = tid >> 3, kv8 = (tid & 7) << 3;

  for (int kt = 0; kt < 4; ++kt) {
    const int k0 = kt * 64;
#pragma unroll
    for (int i = 0; i < 4; ++i) {
      const int r = r0 + i * 32;
      int ga = rowBase + r; ga = ga < HW ? ga : HW - 1;
      *(s16x8*)&As[r][kv8] = *(const s16x8*)(Aq + (size_t)ga * DIM + k0 + kv8);
      int gb = colBase + r; gb = gb < HW ? gb : HW - 1;
      *(s16x8*)&Bs[r][kv8] = *(const s16x8*)(Bk + (size_t)gb * DIM + k0 + kv8);
    }
    __syncthreads();
    mfma_tile<4, 4>(As, Bs, lane, wr, wc, acc);
    __syncthreads();
  }
  float* out = attn + (size_t)b * HW * HW;
#pragma unroll
  for (int n = 0; n < 4; ++n) {
    const int kp = colBase + wc + n * 16 + (lane & 15);
    if (kp >= HW) continue;
    const float sp = sup[b * HW + kp];
#pragma unroll
    for (int m = 0; m < 4; ++m) {
      const int qp = rowBase + wr + m * 16 + ((lane >> 4) << 2);
      if (qp < HW) {
#pragma unroll
        for (int r = 0; r < 4; ++r) out[(size_t)(qp + r) * HW + kp] = acc[m][n][r] + sp;
      }
    }
  }
}

// ---------------- softmax: one block per row, in-place on attn ----------------
__global__ __launch_bounds__(256) void k_softmax(float* __restrict__ attn) {
  const size_t row = blockIdx.x;
  float* rp = attn + row * HW;
  const int t = threadIdx.x;
  f32x4 v[4];
  float m = -3.4e38f;
#pragma unroll
  for (int i = 0; i < 4; ++i) {
    const int idx = t + i * 256;
    if (idx < 900) {
      v[i] = *(const f32x4*)(rp + idx * 4);
      m = fmaxf(m, fmaxf(fmaxf(v[i][0], v[i][1]), fmaxf(v[i][2], v[i][3])));
    }
  }
#pragma unroll
  for (int off = 32; off > 0; off >>= 1) m = fmaxf(m, __shfl_xor(m, off));
  __shared__ float redM[4], redS[4];
  if ((t & 63) == 0) redM[t >> 6] = m;
  __syncthreads();
  m = fmaxf(fmaxf(redM[0], redM[1]), fmaxf(redM[2], redM[3]));
  float s = 0.f;
#pragma unroll
  for (int i = 0; i < 4; ++i) {
    const int idx = t + i * 256;
    if (idx < 900) {
#pragma unroll
      for (int c = 0; c < 4; ++c) { v[i][c] = expf(v[i][c] - m); s += v[i][c]; }
    }
  }
#pragma unroll
  for (int off = 32; off > 0; off >>= 1) s += __shfl_xor(s, off);
  if ((t & 63) == 0) redS[t >> 6] = s;
  __syncthreads();
  const float inv = 1.f / (redS[0] + redS[1] + redS[2] + redS[3]);
#pragma unroll
  for (int i = 0; i < 4; ++i) {
    const int idx = t + i * 256;
    if (idx < 900) {
      f32x4 w = v[i] * inv;
      *(f32x4*)(rp + idx * 4) = w;
    }
  }
}

// ---------------- pv: partial[split] = attn[:,ks:ke] @ vs^T, fp32 partials -------------
__global__ __launch_bounds__(256) void k_pv(
    const float* __restrict__ attn, const h16* __restrict__ vs, float* __restrict__ part) {
  const int tid = threadIdx.x, lane = tid & 63, wid = tid >> 6;
  const int wc = wid << 6;                       // 4 waves: 64 rows x 64 cols each
  const int rowBase = blockIdx.x * 64;           // q pixel
  const int split = blockIdx.y;
  const int b = blockIdx.z;
  const float* Ab = attn + (size_t)b * HW * HW;
  const h16* Bv = vs + (size_t)b * DIM * HWP;

  __shared__ h16 As[64][LDK];
  __shared__ h16 Bs[256][LDK];
  f32x4 acc[4][4] = {};

  const int a_r = tid >> 4, a_kv = (tid & 15) << 2;
  const int b_r = tid >> 3, b_kv = (tid & 7) << 3;
  const int kbeg = split ? 1792 : 0;
  const int kend = split ? HW : 1792;

  for (int k0 = kbeg; k0 < kend; k0 += 64) {
    const int kc = k0 + a_kv;
#pragma unroll
    for (int i = 0; i < 4; ++i) {
      const int r = a_r + i * 16;
      int ga = rowBase + r; ga = ga < HW ? ga : HW - 1;
      h16x4 h = {(h16)0.f, (h16)0.f, (h16)0.f, (h16)0.f};
      if (kc < HW) {
        f32x4 vv = *(const f32x4*)(Ab + (size_t)ga * HW + kc);
        h = (h16x4){(h16)vv[0], (h16)vv[1], (h16)vv[2], (h16)vv[3]};
      }
      *(h16x4*)&As[r][a_kv] = h;
    }
#pragma unroll
    for (int i = 0; i < 8; ++i) {
      const int d = b_r + i * 32;
      *(s16x8*)&Bs[d][b_kv] = *(const s16x8*)(Bv + (size_t)d * HWP + k0 + b_kv);
    }
    __syncthreads();
    mfma_tile<4, 4>(As, Bs, lane, 0, wc, acc);
    __syncthreads();
  }
  float* dst = part + (size_t)(split * 4 + b) * HW * DIM;
#pragma unroll
  for (int m = 0; m < 4; ++m) {
    const int pix0 = rowBase + m * 16 + ((lane >> 4) << 2);
#pragma unroll
    for (int n = 0; n < 4; ++n) {
      const int d = wc + n * 16 + (lane & 15);
#pragma unroll
      for (int r = 0; r < 4; ++r)
        if (pix0 + r < HW) dst[(size_t)(pix0 + r) * DIM + d] = acc[m][n][r];
    }
  }
}

// ---------------- pvred: ov = fp16(part0 + part1) ----------------
__global__ __launch_bounds__(256) void k_pvred(const float* __restrict__ part,
                                               h16* __restrict__ ov) {
  const size_t base = ((size_t)blockIdx.x * 256 + threadIdx.x) * 4;
  f32x4 p0 = *(const f32x4*)&part[base];
  f32x4 p1 = *(const f32x4*)&part[(size_t)4 * HW * DIM + base];
  f32x4 s = p0 + p1;
  h16x4 h = {(h16)s[0], (h16)s[1], (h16)s[2], (h16)s[3]};
  *(h16x4*)&ov[base] = h;
}

// ---------------- final: relu(Wf @ [ov|vq] + b) -> [b][o][pix] fp32 -------------------
__global__ __launch_bounds__(256) void k_final(
    const h16* __restrict__ ov, const h16* __restrict__ vq,
    const h16* __restrict__ Wf16, const float* __restrict__ bfin,
    float* __restrict__ outF) {
  const int tid = threadIdx.x, lane = tid & 63, wid = tid >> 6;
  const int wr = (wid >> 1) << 5, wc = (wid & 1) << 6;   // 2x2 waves of 32x64
  const int rowBase = blockIdx.x * 64;           // pixel
  const int colBase = blockIdx.y * 128;          // o
  const int b = blockIdx.z;
  const h16* Aov = ov + (size_t)b * HW * DIM;
  const h16* Avq = vq + (size_t)b * HW * DIM;

  __shared__ h16 As[64][LDK];
  __shared__ h16 Bs[128][LDK];
  f32x4 acc[2][4] = {};

  const int a_r = tid >> 3, a_kv = (tid & 7) << 3;

  for (int kt = 0; kt < 8; ++kt) {
    const int k0 = kt * 64;
    const h16* Asrc = (k0 < 256) ? Aov : Avq;
    const int ak = k0 & 255;
#pragma unroll
    for (int i = 0; i < 2; ++i) {
      const int r = a_r + i * 32;
      int ga = rowBase + r; ga = ga < HW ? ga : HW - 1;
      *(s16x8*)&As[r][a_kv] = *(const s16x8*)(Asrc + (size_t)ga * DIM + ak + a_kv);
    }
#pragma unroll
    for (int i = 0; i < 4; ++i) {
      const int r = a_r + i * 32;
      *(s16x8*)&Bs[r][a_kv] = *(const s16x8*)(Wf16 + (size_t)(colBase + r) * 512 + k0 + a_kv);
    }
    __syncthreads();
    mfma_tile<2, 4>(As, Bs, lane, wr, wc, acc);
    __syncthreads();
  }
  float* dst = outF + (size_t)b * DIM * HW;
#pragma unroll
  for (int n = 0; n < 4; ++n) {
    const int o = colBase + wc + n * 16 + (lane & 15);
    const float bb = bfin[o];
#pragma unroll
    for (int m = 0; m < 2; ++m) {
      const int pix0 = rowBase + wr + m * 16 + ((lane >> 4) << 2);
      if (pix0 < HW) {
        f32x4 v;
#pragma unroll
        for (int r = 0; r < 4; ++r) v[r] = fmaxf(acc[m][n][r] + bb, 0.f);
        *(f32x4*)(dst + (size_t)o * HW + pix0) = v;
      }
    }
  }
}

extern "C" void kernel_launch(void* const* d_in, const int* in_sizes, int n_in,
                              void* d_out, int out_size, void* d_ws, size_t ws_size,
                              hipStream_t stream) {
  (void)in_sizes; (void)n_in; (void)out_size; (void)ws_size;
  const float* featS  = (const float*)d_in[0];
  const float* featQ  = (const float*)d_in[1];
  const float* mask   = (const float*)d_in[2];
  const float* Wlpf   = (const float*)d_in[3];
  const float* Wsupp  = (const float*)d_in[4];
  const float* Wquery = (const float*)d_in[5];
  const float* Wfin   = (const float*)d_in[6];
  const float* bfin   = (const float*)d_in[7];

  float* outF = (float*)d_out;
  float* attn = outF + (size_t)4 * DIM * HW;     // output 1 region doubles as logits scratch

  char* w = (char*)d_ws;
  h16* qbuf = (h16*)w;  w += (size_t)4 * HW * DIM * 2;
  h16* kbuf = (h16*)w;  w += (size_t)4 * HW * DIM * 2;
  h16* vs   = (h16*)w;  w += (size_t)4 * DIM * HWP * 2;
  h16* vq   = (h16*)w;  w += (size_t)4 * HW * DIM * 2;
  h16* ov   = (h16*)w;  w += (size_t)4 * HW * DIM * 2;
  float* part = (float*)w;  w += (size_t)2 * 4 * HW * DIM * 4;
  h16* Wl16 = (h16*)w;  w += (size_t)NW * 2;
  h16* Ws16 = (h16*)w;  w += (size_t)NW * 2;
  h16* Wq16 = (h16*)w;  w += (size_t)NW * 2;
  h16* Wf16 = (h16*)w;  w += (size_t)NWF * 2;
  float* sup = (float*)w;

  k_prep<<<dim3((NPREP + 255) / 256), 256, 0, stream>>>(
      mask, Wlpf, Wsupp, Wquery, Wfin, sup, Wl16, Ws16, Wq16, Wf16, vs);
  k_conv<<<dim3(4, 29, 8), 256, 0, stream>>>(Wl16, Ws16, Wq16, featS, featQ,
                                             vs, vq, kbuf, qbuf);
  k_qk<<<dim3(29, 29, 4), 256, 0, stream>>>(qbuf, kbuf, sup, attn);
  k_softmax<<<dim3(4 * HW), 256, 0, stream>>>(attn);
  k_pv<<<dim3(57, 2, 4), 256, 0, stream>>>(attn, vs, part);
  k_pvred<<<dim3(3600), 256, 0, stream>>>(part, ov);
  k_final<<<dim3(57, 2, 4), 256, 0, stream>>>(ov, vq, Wf16, bfin, outF);
}